// Round 2
// baseline (762.870 us; speedup 1.0000x reference)
//
#include <hip/hip_runtime.h>

typedef __bf16 bf16x8 __attribute__((ext_vector_type(8)));
typedef float  f32x4  __attribute__((ext_vector_type(4)));

#define MFMA16(a, b, c) __builtin_amdgcn_mfma_f32_16x16x32_bf16((a), (b), (c), 0, 0, 0)

// ---- problem geometry ----
constexpr int Cdim = 192, NHd = 6;
constexpr int Dd = 46, Hh = 47, Wl = 48;
constexpr int HWst = Hh * Wl;            // 2256
constexpr int NWIN_PER_B = 12 * 12 * 12; // 1728
constexpr int NBLK = 2 * NWIN_PER_B;     // 3456

// ---- LDS layout (bytes) ----
constexpr int XW_LD = 200;  // 192 + 8 pad (bf16)
constexpr int QK_LD = 40;   // 32 + 8
constexpr int VT_LD = 72;   // 64 + 8
constexpr int P_LD  = 72;
constexpr int XW_OFF  = 0;                 // [64][200] bf16 = 25600 (also attn_out)
constexpr int QK_OFF  = 25600;             // [2][6][64][40] bf16 = 61440
constexpr int VT_OFF  = QK_OFF + 61440;    // [6][32][72] bf16 = 27648
constexpr int P_OFF   = VT_OFF + 27648;    // [4][16][72] bf16 = 9216
constexpr int RPB_OFF = P_OFF + 9216;      // 343*6 f32 = 8232
constexpr int LDS_TOTAL = RPB_OFF + 8256;  // 132160

__device__ inline bf16x8 cvt8(const float* __restrict__ p) {
  f32x4 u0 = *(const f32x4*)p;
  f32x4 u1 = *(const f32x4*)(p + 4);
  bf16x8 r;
  r[0] = (__bf16)u0[0]; r[1] = (__bf16)u0[1]; r[2] = (__bf16)u0[2]; r[3] = (__bf16)u0[3];
  r[4] = (__bf16)u1[0]; r[5] = (__bf16)u1[1]; r[6] = (__bf16)u1[2]; r[7] = (__bf16)u1[3];
  return r;
}

__global__ __launch_bounds__(256, 1) void winattn_kernel(
    const float* __restrict__ x, const float* __restrict__ qkv_w,
    const float* __restrict__ qkv_b, const float* __restrict__ proj_w,
    const float* __restrict__ proj_b, const float* __restrict__ rpb,
    float* __restrict__ out)
{
  extern __shared__ __align__(16) char smem[];
  __bf16* xw  = (__bf16*)(smem + XW_OFF);   // [64][XW_LD]  (reused as attn_out)
  __bf16* qk  = (__bf16*)(smem + QK_OFF);   // [2][6][64][QK_LD]
  __bf16* vt  = (__bf16*)(smem + VT_OFF);   // [6][32][VT_LD]  (v transposed: [e][m])
  __bf16* pl  = (__bf16*)(smem + P_OFF);    // [4][16][P_LD]  per-wave P scratch
  float*  rps = (float*)(smem + RPB_OFF);   // [343*6]

  const f32x4 fz = {0.f, 0.f, 0.f, 0.f};

  const int tid  = threadIdx.x;
  const int lane = tid & 63;
  const int wv   = tid >> 6;
  const int li   = lane & 15;
  const int g    = lane >> 4;

  const int wid = blockIdx.x;
  const int b   = wid / NWIN_PER_B;
  const int wr  = wid % NWIN_PER_B;
  const int dwi = wr / 144;
  const int hwi = (wr / 12) % 12;
  const int wwi = wr % 12;
  const int d0 = dwi * 4, h0 = hwi * 4, w0 = wwi * 4;

  // ---- stage rpb table ----
  for (int i = tid; i < 343 * NHd; i += 256) rps[i] = rpb[i];

  // ---- stage x window -> xw bf16 [n][c] (zero-pad d>=46, h>=47) ----
  if (tid < Cdim) {
    const int c = tid;
    const float* xb = x + (size_t)(b * Cdim + c) * Dd * HWst;
    #pragma unroll
    for (int dd = 0; dd < 4; ++dd) {
      #pragma unroll
      for (int hh = 0; hh < 4; ++hh) {
        const int d = d0 + dd, h = h0 + hh;
        f32x4 v = fz;
        if (d < Dd && h < Hh) v = *(const f32x4*)(xb + (size_t)d * HWst + h * Wl + w0);
        const int nb = (dd * 16 + hh * 4) * XW_LD + c;
        xw[nb]              = (__bf16)v[0];
        xw[nb + XW_LD]      = (__bf16)v[1];
        xw[nb + 2 * XW_LD]  = (__bf16)v[2];
        xw[nb + 3 * XW_LD]  = (__bf16)v[3];
      }
    }
  }
  __syncthreads();

  // ---- QKV GEMM: (64x192) @ (192x576); this wave owns col tiles [wv*9, wv*9+9) ----
  {
    f32x4 acc[9][4];
    #pragma unroll
    for (int i = 0; i < 9; ++i)
      #pragma unroll
      for (int r = 0; r < 4; ++r) acc[i][r] = fz;

    #pragma unroll
    for (int kk = 0; kk < 6; ++kk) {
      const int k0 = kk * 32 + g * 8;
      bf16x8 af[4];
      #pragma unroll
      for (int rt = 0; rt < 4; ++rt)
        af[rt] = *(const bf16x8*)&xw[(rt * 16 + li) * XW_LD + k0];
      #pragma unroll
      for (int i = 0; i < 9; ++i) {
        const int j = (wv * 9 + i) * 16 + li;
        bf16x8 bf = cvt8(qkv_w + j * Cdim + k0);
        #pragma unroll
        for (int rt = 0; rt < 4; ++rt)
          acc[i][rt] = MFMA16(af[rt], bf, acc[i][rt]);
      }
    }
    // scatter D tiles into q/k row-major, v transposed
    #pragma unroll
    for (int i = 0; i < 9; ++i) {
      const int j0   = (wv * 9 + i) * 16;
      const int part = j0 / 192;
      const int hh   = (j0 % 192) / 32;
      const int e    = (j0 % 32) + li;
      const float qb = qkv_b[j0 + li];
      #pragma unroll
      for (int rt = 0; rt < 4; ++rt) {
        #pragma unroll
        for (int r = 0; r < 4; ++r) {
          const float val = acc[i][rt][r] + qb;
          const int n = rt * 16 + g * 4 + r;
          if (part < 2) qk[((part * NHd + hh) * 64 + n) * QK_LD + e] = (__bf16)val;
          else          vt[(hh * 32 + e) * VT_LD + n] = (__bf16)val;
        }
      }
    }
  }
  __syncthreads();

  // ---- attention: this wave owns query rows [wv*16, wv*16+16), all heads ----
  {
    const float scale = 0.17677669529663687f;  // 32^-0.5
    __bf16* pw = pl + wv * 16 * P_LD;
    #pragma unroll 1
    for (int h = 0; h < NHd; ++h) {
      // S = Q K^T  (K=32 in a single MFMA per 16x16 tile)
      bf16x8 aq = *(const bf16x8*)&qk[(h * 64 + wv * 16 + li) * QK_LD + g * 8];
      f32x4 s[4];
      #pragma unroll
      for (int ct = 0; ct < 4; ++ct) {
        bf16x8 bk = *(const bf16x8*)&qk[((NHd + h) * 64 + ct * 16 + li) * QK_LD + g * 8];
        s[ct] = MFMA16(aq, bk, fz);
      }
      // bias + scale, row max (rows live in 16-lane groups)
      float t[4][4], rm[4] = {-3e38f, -3e38f, -3e38f, -3e38f};
      #pragma unroll
      for (int ct = 0; ct < 4; ++ct) {
        const int m = ct * 16 + li;
        const int d2 = m >> 4, h2 = (m >> 2) & 3, w2 = m & 3;
        #pragma unroll
        for (int r = 0; r < 4; ++r) {
          const int n = wv * 16 + g * 4 + r;
          const int d1 = n >> 4, h1 = (n >> 2) & 3, w1 = n & 3;
          const int idx = (d1 - d2 + 3) * 49 + (h1 - h2 + 3) * 7 + (w1 - w2 + 3);
          const float tv = s[ct][r] * scale + rps[idx * NHd + h];
          t[ct][r] = tv;
          rm[r] = fmaxf(rm[r], tv);
        }
      }
      #pragma unroll
      for (int r = 0; r < 4; ++r) {
        rm[r] = fmaxf(rm[r], __shfl_xor(rm[r], 1, 16));
        rm[r] = fmaxf(rm[r], __shfl_xor(rm[r], 2, 16));
        rm[r] = fmaxf(rm[r], __shfl_xor(rm[r], 4, 16));
        rm[r] = fmaxf(rm[r], __shfl_xor(rm[r], 8, 16));
      }
      float rs[4] = {0, 0, 0, 0};
      #pragma unroll
      for (int ct = 0; ct < 4; ++ct)
        #pragma unroll
        for (int r = 0; r < 4; ++r) {
          const float p = __expf(t[ct][r] - rm[r]);
          t[ct][r] = p;
          rs[r] += p;
        }
      #pragma unroll
      for (int r = 0; r < 4; ++r) {
        rs[r] += __shfl_xor(rs[r], 1, 16);
        rs[r] += __shfl_xor(rs[r], 2, 16);
        rs[r] += __shfl_xor(rs[r], 4, 16);
        rs[r] += __shfl_xor(rs[r], 8, 16);
      }
      // P -> bf16 via wave-private LDS (transpose to A-fragment layout)
      #pragma unroll
      for (int ct = 0; ct < 4; ++ct)
        #pragma unroll
        for (int r = 0; r < 4; ++r)
          pw[(g * 4 + r) * P_LD + ct * 16 + li] = (__bf16)t[ct][r];
      // O = P V
      f32x4 o[2] = {fz, fz};
      #pragma unroll
      for (int kk = 0; kk < 2; ++kk) {
        bf16x8 ap = *(const bf16x8*)&pw[li * P_LD + kk * 32 + g * 8];
        #pragma unroll
        for (int ct = 0; ct < 2; ++ct) {
          bf16x8 bv = *(const bf16x8*)&vt[(h * 32 + ct * 16 + li) * VT_LD + kk * 32 + g * 8];
          o[ct] = MFMA16(ap, bv, o[ct]);
        }
      }
      float inv[4];
      #pragma unroll
      for (int r = 0; r < 4; ++r) inv[r] = 1.f / rs[r];
      #pragma unroll
      for (int ct = 0; ct < 2; ++ct)
        #pragma unroll
        for (int r = 0; r < 4; ++r) {
          const int n = wv * 16 + g * 4 + r;
          const int c = h * 32 + ct * 16 + li;
          xw[n * XW_LD + c] = (__bf16)(o[ct][r] * inv[r]);  // attn_out reuses xw
        }
    }
  }
  __syncthreads();

  // ---- proj GEMM: (64x192) @ (192x192); this wave owns col tiles [wv*3, wv*3+3) ----
  {
    f32x4 acc[3][4];
    #pragma unroll
    for (int i = 0; i < 3; ++i)
      #pragma unroll
      for (int r = 0; r < 4; ++r) acc[i][r] = fz;

    #pragma unroll
    for (int kk = 0; kk < 6; ++kk) {
      const int k0 = kk * 32 + g * 8;
      bf16x8 af[4];
      #pragma unroll
      for (int rt = 0; rt < 4; ++rt)
        af[rt] = *(const bf16x8*)&xw[(rt * 16 + li) * XW_LD + k0];
      #pragma unroll
      for (int i = 0; i < 3; ++i) {
        const int c = (wv * 3 + i) * 16 + li;
        bf16x8 bf = cvt8(proj_w + c * Cdim + k0);
        #pragma unroll
        for (int rt = 0; rt < 4; ++rt)
          acc[i][rt] = MFMA16(af[rt], bf, acc[i][rt]);
      }
    }
    // epilogue: +proj_b, scatter with crop; rows of a tile are 4 consecutive w -> float4
    #pragma unroll
    for (int i = 0; i < 3; ++i) {
      const int c = (wv * 3 + i) * 16 + li;
      const float pb = proj_b[c];
      #pragma unroll
      for (int rt = 0; rt < 4; ++rt) {
        const int d = d0 + rt, h = h0 + g;
        if (d < Dd && h < Hh) {
          f32x4 vv = {acc[i][rt][0] + pb, acc[i][rt][1] + pb,
                      acc[i][rt][2] + pb, acc[i][rt][3] + pb};
          *(f32x4*)(out + ((size_t)(b * Cdim + c) * Dd + d) * HWst + h * Wl + w0) = vv;
        }
      }
    }
  }
}

extern "C" void kernel_launch(void* const* d_in, const int* in_sizes, int n_in,
                              void* d_out, int out_size, void* d_ws, size_t ws_size,
                              hipStream_t stream) {
  const float* x      = (const float*)d_in[0];
  const float* qkv_w  = (const float*)d_in[1];
  const float* qkv_b  = (const float*)d_in[2];
  const float* proj_w = (const float*)d_in[3];
  const float* proj_b  = (const float*)d_in[4];
  const float* rpb    = (const float*)d_in[5];
  float* out = (float*)d_out;

  (void)hipFuncSetAttribute(reinterpret_cast<const void*>(winattn_kernel),
                            hipFuncAttributeMaxDynamicSharedMemorySize, LDS_TOTAL);
  hipLaunchKernelGGL(winattn_kernel, dim3(NBLK), dim3(256), LDS_TOTAL, stream,
                     x, qkv_w, qkv_b, proj_w, proj_b, rpb, out);
}

// Round 3
// 492.319 us; speedup vs baseline: 1.5495x; 1.5495x over previous
//
#include <hip/hip_runtime.h>

typedef __bf16 bf16x8 __attribute__((ext_vector_type(8)));
typedef float  f32x4  __attribute__((ext_vector_type(4)));

#define MFMA16(a, b, c) __builtin_amdgcn_mfma_f32_16x16x32_bf16((a), (b), (c), 0, 0, 0)

// ---- problem geometry ----
constexpr int Cdim = 192, NHd = 6;
constexpr int Dd = 46, Hh = 47, Wl = 48;
constexpr int HWst = Hh * Wl;            // 2256
constexpr int NWIN_PER_B = 12 * 12 * 12; // 1728
constexpr int NBLK = 2 * NWIN_PER_B;     // 3456
constexpr int NTHR = 768;                // 12 waves

// ---- LDS layout ----
constexpr int XW_LD = 200;  // x window / attn_out row stride (bf16 elems)
constexpr int QK_LD = 36;   // q/k row stride (32 + 4)
constexpr int VT_LD = 68;   // v^T row stride (64 + 4)
constexpr int P_LD  = 68;   // P row stride
constexpr int XW_OFF  = 0;                  // [64][200] bf16 = 25600
constexpr int Q_OFF   = 25600;              // [6][64][36] bf16 = 27648
constexpr int K_OFF   = Q_OFF + 27648;      // [6][64][36] bf16 = 27648
constexpr int VT_OFF  = K_OFF + 27648;      // [6][32][68] bf16 = 26112
constexpr int P_OFF   = VT_OFF + 26112;     // [12][16][68] bf16 = 26112
constexpr int RPB_OFF = P_OFF + 26112;      // 2058 f32 = 8232
constexpr int LDS_TOTAL = RPB_OFF + 8256;   // 141376

// ws layout (bf16 weights)
constexpr int WQ_ELEMS = 576 * 192;   // 110592
constexpr int WP_ELEMS = 192 * 192;   // 36864
constexpr size_t WS_NEED = (size_t)(WQ_ELEMS + WP_ELEMS) * 2;

__device__ inline bf16x8 cvt8(const float* __restrict__ p) {
  f32x4 u0 = *(const f32x4*)p;
  f32x4 u1 = *(const f32x4*)(p + 4);
  bf16x8 r;
  r[0] = (__bf16)u0[0]; r[1] = (__bf16)u0[1]; r[2] = (__bf16)u0[2]; r[3] = (__bf16)u0[3];
  r[4] = (__bf16)u1[0]; r[5] = (__bf16)u1[1]; r[6] = (__bf16)u1[2]; r[7] = (__bf16)u1[3];
  return r;
}

__global__ __launch_bounds__(256) void convert_w_kernel(
    const float* __restrict__ qkv_w, const float* __restrict__ proj_w,
    __bf16* __restrict__ wq, __bf16* __restrict__ wp) {
  const int i = blockIdx.x * 256 + threadIdx.x;
  if (i < WQ_ELEMS) wq[i] = (__bf16)qkv_w[i];
  if (i < WP_ELEMS) wp[i] = (__bf16)proj_w[i];
}

template <bool WB>
__global__ __launch_bounds__(NTHR, 3) void winattn_kernel(
    const float* __restrict__ x, const float* __restrict__ qkv_w,
    const float* __restrict__ qkv_b, const float* __restrict__ proj_w,
    const float* __restrict__ proj_b, const float* __restrict__ rpb,
    const __bf16* __restrict__ wq, const __bf16* __restrict__ wp,
    float* __restrict__ out)
{
  extern __shared__ __align__(16) char smem[];
  __bf16* xw  = (__bf16*)(smem + XW_OFF);   // [64][XW_LD]  x window, then attn_out
  __bf16* qs  = (__bf16*)(smem + Q_OFF);    // [6][64][QK_LD]
  __bf16* ks  = (__bf16*)(smem + K_OFF);    // [6][64][QK_LD]
  __bf16* vt  = (__bf16*)(smem + VT_OFF);   // [6][32][VT_LD] (v transposed [e][m])
  __bf16* pl  = (__bf16*)(smem + P_OFF);    // [12][16][P_LD] per-wave P
  float*  rps = (float*)(smem + RPB_OFF);   // [343*6]

  const f32x4 fz = {0.f, 0.f, 0.f, 0.f};

  const int tid  = threadIdx.x;
  const int lane = tid & 63;
  const int wv   = tid >> 6;        // 0..11
  const int hq   = wv >> 1;         // head 0..5
  const int half = wv & 1;          // row half 0..1
  const int li   = lane & 15;
  const int g    = lane >> 4;

  // XCD-aware bijective swizzle (3456 = 8 * 432)
  const int bid = blockIdx.x;
  const int wid = (bid & 7) * (NBLK / 8) + (bid >> 3);
  const int b   = wid / NWIN_PER_B;
  const int wr  = wid % NWIN_PER_B;
  const int dwi = wr / 144;
  const int hwi = (wr / 12) % 12;
  const int wwi = wr % 12;
  const int d0 = dwi * 4, h0 = hwi * 4, w0 = wwi * 4;

  // ---- stage rpb table ----
  for (int i = tid; i < 343 * NHd; i += NTHR) rps[i] = rpb[i];

  // ---- stage x window -> xw bf16 [n][c] (zero-pad d>=46, h>=47) ----
  #pragma unroll
  for (int rep = 0; rep < 4; ++rep) {
    const int task = rep * NTHR + tid;    // < 3072
    const int c  = task % Cdim;
    const int ph = task / Cdim;           // 0..15
    const int dd = ph >> 2, hh2 = ph & 3;
    const int d = d0 + dd, hsp = h0 + hh2;
    f32x4 v = fz;
    if (d < Dd && hsp < Hh)
      v = *(const f32x4*)(x + ((size_t)(b * Cdim + c) * Dd + d) * HWst + hsp * Wl + w0);
    const int nb = (dd * 16 + hh2 * 4) * XW_LD + c;
    xw[nb]             = (__bf16)v[0];
    xw[nb + XW_LD]     = (__bf16)v[1];
    xw[nb + 2 * XW_LD] = (__bf16)v[2];
    xw[nb + 3 * XW_LD] = (__bf16)v[3];
  }
  __syncthreads();

  // ---- QKV GEMM: wave (hq,half) computes col tiles {q,k,v}x{2} for head hq,
  //      rows [half*32, half*32+32) ----
  {
    f32x4 acc[6][2];
    #pragma unroll
    for (int it = 0; it < 6; ++it)
      #pragma unroll
      for (int rr = 0; rr < 2; ++rr) acc[it][rr] = fz;

    #pragma unroll
    for (int kk = 0; kk < 6; ++kk) {
      const int k0 = kk * 32 + g * 8;
      bf16x8 af[2];
      #pragma unroll
      for (int rr = 0; rr < 2; ++rr)
        af[rr] = *(const bf16x8*)&xw[((half * 2 + rr) * 16 + li) * XW_LD + k0];
      #pragma unroll
      for (int it = 0; it < 6; ++it) {
        const int T = (it >> 1) * 12 + hq * 2 + (it & 1);
        const int j = T * 16 + li;
        bf16x8 bf;
        if constexpr (WB) bf = *(const bf16x8*)(wq + j * Cdim + k0);
        else              bf = cvt8(qkv_w + j * Cdim + k0);
        #pragma unroll
        for (int rr = 0; rr < 2; ++rr)
          acc[it][rr] = MFMA16(af[rr], bf, acc[it][rr]);
      }
    }
    // scatter: q,k row-major per head; v transposed
    #pragma unroll
    for (int it = 0; it < 6; ++it) {
      const int part = it >> 1;            // 0=q 1=k 2=v
      const int e16  = (it & 1) * 16;
      const int j0   = (part * 12 + hq * 2 + (it & 1)) * 16;
      const float qb = qkv_b[j0 + li];
      #pragma unroll
      for (int rr = 0; rr < 2; ++rr) {
        const int rb = half * 2 + rr;
        #pragma unroll
        for (int r = 0; r < 4; ++r) {
          const float val = acc[it][rr][r] + qb;
          const int n = rb * 16 + g * 4 + r;
          if (part == 0)      qs[(hq * 64 + n) * QK_LD + e16 + li] = (__bf16)val;
          else if (part == 1) ks[(hq * 64 + n) * QK_LD + e16 + li] = (__bf16)val;
          else                vt[(hq * 32 + e16 + li) * VT_LD + n] = (__bf16)val;
        }
      }
    }
  }
  __syncthreads();   // k/v shared across the head's two waves; xw reads done

  // ---- attention: wave (hq,half) handles rows [half*32, half*32+32) of head hq ----
  {
    const float scale = 0.17677669529663687f;  // 32^-0.5
    __bf16* pw = pl + wv * 16 * P_LD;
    #pragma unroll 1
    for (int rr = 0; rr < 2; ++rr) {
      const int rb = half * 2 + rr;
      bf16x8 aq = *(const bf16x8*)&qs[(hq * 64 + rb * 16 + li) * QK_LD + g * 8];
      f32x4 s[4];
      #pragma unroll
      for (int ct = 0; ct < 4; ++ct) {
        bf16x8 bk = *(const bf16x8*)&ks[(hq * 64 + ct * 16 + li) * QK_LD + g * 8];
        s[ct] = MFMA16(aq, bk, fz);
      }
      float t[4][4], rm[4] = {-3e38f, -3e38f, -3e38f, -3e38f};
      #pragma unroll
      for (int ct = 0; ct < 4; ++ct) {
        const int m = ct * 16 + li;
        const int d2 = m >> 4, h2 = (m >> 2) & 3, w2 = m & 3;
        #pragma unroll
        for (int r = 0; r < 4; ++r) {
          const int n = rb * 16 + g * 4 + r;
          const int d1 = n >> 4, h1 = (n >> 2) & 3, w1 = n & 3;
          const int idx = (d1 - d2 + 3) * 49 + (h1 - h2 + 3) * 7 + (w1 - w2 + 3);
          const float tv = s[ct][r] * scale + rps[idx * NHd + hq];
          t[ct][r] = tv;
          rm[r] = fmaxf(rm[r], tv);
        }
      }
      #pragma unroll
      for (int r = 0; r < 4; ++r) {
        rm[r] = fmaxf(rm[r], __shfl_xor(rm[r], 1, 16));
        rm[r] = fmaxf(rm[r], __shfl_xor(rm[r], 2, 16));
        rm[r] = fmaxf(rm[r], __shfl_xor(rm[r], 4, 16));
        rm[r] = fmaxf(rm[r], __shfl_xor(rm[r], 8, 16));
      }
      float rs[4] = {0, 0, 0, 0};
      #pragma unroll
      for (int ct = 0; ct < 4; ++ct)
        #pragma unroll
        for (int r = 0; r < 4; ++r) {
          const float p = __expf(t[ct][r] - rm[r]);
          t[ct][r] = p;
          rs[r] += p;
        }
      #pragma unroll
      for (int r = 0; r < 4; ++r) {
        rs[r] += __shfl_xor(rs[r], 1, 16);
        rs[r] += __shfl_xor(rs[r], 2, 16);
        rs[r] += __shfl_xor(rs[r], 4, 16);
        rs[r] += __shfl_xor(rs[r], 8, 16);
      }
      // P -> bf16 via wave-private LDS (transpose to A-fragment layout)
      #pragma unroll
      for (int ct = 0; ct < 4; ++ct)
        #pragma unroll
        for (int r = 0; r < 4; ++r)
          pw[(g * 4 + r) * P_LD + ct * 16 + li] = (__bf16)t[ct][r];
      // O = P V
      f32x4 o[2] = {fz, fz};
      #pragma unroll
      for (int kk = 0; kk < 2; ++kk) {
        bf16x8 ap = *(const bf16x8*)&pw[li * P_LD + kk * 32 + g * 8];
        #pragma unroll
        for (int ct = 0; ct < 2; ++ct) {
          bf16x8 bv = *(const bf16x8*)&vt[(hq * 32 + ct * 16 + li) * VT_LD + kk * 32 + g * 8];
          o[ct] = MFMA16(ap, bv, o[ct]);
        }
      }
      float inv[4];
      #pragma unroll
      for (int r = 0; r < 4; ++r) inv[r] = 1.f / rs[r];
      #pragma unroll
      for (int ct = 0; ct < 2; ++ct)
        #pragma unroll
        for (int r = 0; r < 4; ++r) {
          const int n = rb * 16 + g * 4 + r;
          const int c = hq * 32 + ct * 16 + li;
          xw[n * XW_LD + c] = (__bf16)(o[ct][r] * inv[r]);
        }
    }
  }
  __syncthreads();

  // ---- proj GEMM: wave wv owns col tile wv (c = wv*16+li) ----
  {
    f32x4 acc[4];
    #pragma unroll
    for (int rt = 0; rt < 4; ++rt) acc[rt] = fz;
    const int c = wv * 16 + li;

    #pragma unroll
    for (int kk = 0; kk < 6; ++kk) {
      const int k0 = kk * 32 + g * 8;
      bf16x8 bf;
      if constexpr (WB) bf = *(const bf16x8*)(wp + c * Cdim + k0);
      else              bf = cvt8(proj_w + c * Cdim + k0);
      #pragma unroll
      for (int rt = 0; rt < 4; ++rt) {
        bf16x8 af = *(const bf16x8*)&xw[(rt * 16 + li) * XW_LD + k0];
        acc[rt] = MFMA16(af, bf, acc[rt]);
      }
    }
    const float pb = proj_b[c];
    #pragma unroll
    for (int rt = 0; rt < 4; ++rt) {
      const int d = d0 + rt, hsp = h0 + g;
      if (d < Dd && hsp < Hh) {
        f32x4 vv = {acc[rt][0] + pb, acc[rt][1] + pb, acc[rt][2] + pb, acc[rt][3] + pb};
        *(f32x4*)(out + ((size_t)(b * Cdim + c) * Dd + d) * HWst + hsp * Wl + w0) = vv;
      }
    }
  }
}

extern "C" void kernel_launch(void* const* d_in, const int* in_sizes, int n_in,
                              void* d_out, int out_size, void* d_ws, size_t ws_size,
                              hipStream_t stream) {
  const float* x      = (const float*)d_in[0];
  const float* qkv_w  = (const float*)d_in[1];
  const float* qkv_b  = (const float*)d_in[2];
  const float* proj_w = (const float*)d_in[3];
  const float* proj_b = (const float*)d_in[4];
  const float* rpb    = (const float*)d_in[5];
  float* out = (float*)d_out;

  if (ws_size >= WS_NEED) {
    __bf16* wq = (__bf16*)d_ws;
    __bf16* wp = wq + WQ_ELEMS;
    convert_w_kernel<<<(WQ_ELEMS + 255) / 256, 256, 0, stream>>>(qkv_w, proj_w, wq, wp);
    (void)hipFuncSetAttribute(reinterpret_cast<const void*>(&winattn_kernel<true>),
                              hipFuncAttributeMaxDynamicSharedMemorySize, LDS_TOTAL);
    winattn_kernel<true><<<NBLK, NTHR, LDS_TOTAL, stream>>>(
        x, qkv_w, qkv_b, proj_w, proj_b, rpb, wq, wp, out);
  } else {
    (void)hipFuncSetAttribute(reinterpret_cast<const void*>(&winattn_kernel<false>),
                              hipFuncAttributeMaxDynamicSharedMemorySize, LDS_TOTAL);
    winattn_kernel<false><<<NBLK, NTHR, LDS_TOTAL, stream>>>(
        x, qkv_w, qkv_b, proj_w, proj_b, rpb, nullptr, nullptr, out);
  }
}

// Round 4
// 479.289 us; speedup vs baseline: 1.5917x; 1.0272x over previous
//
#include <hip/hip_runtime.h>

typedef __bf16 bf16x8 __attribute__((ext_vector_type(8)));
typedef float  f32x4  __attribute__((ext_vector_type(4)));

#define MFMA16(a, b, c) __builtin_amdgcn_mfma_f32_16x16x32_bf16((a), (b), (c), 0, 0, 0)

// ---- problem geometry ----
constexpr int Cdim = 192, NHd = 6;
constexpr int Dd = 46, Hh = 47, Wl = 48;
constexpr int HWst = Hh * Wl;            // 2256
constexpr int NWIN_PER_B = 12 * 12 * 12; // 1728
constexpr int NBLK = 2 * NWIN_PER_B;     // 3456
constexpr float SCALE = 0.17677669529663687f;  // 32^-0.5

// ---- workspace layout (bf16 elems) ----
constexpr int WQ_ELEMS = 576 * 192;
constexpr int WP_ELEMS = 192 * 192;
constexpr size_t QKV_PART = (size_t)NBLK * 64 * 192;
constexpr size_t OFF_WQ = 0;
constexpr size_t OFF_WP = OFF_WQ + WQ_ELEMS;
constexpr size_t OFF_Q  = OFF_WP + WP_ELEMS;
constexpr size_t OFF_K  = OFF_Q + QKV_PART;
constexpr size_t OFF_V  = OFF_K + QKV_PART;
constexpr size_t WS_FULL = (OFF_V + QKV_PART) * 2;
constexpr size_t WS_W    = (size_t)(WQ_ELEMS + WP_ELEMS) * 2;

__device__ inline bf16x8 cvt8(const float* __restrict__ p) {
  f32x4 u0 = *(const f32x4*)p;
  f32x4 u1 = *(const f32x4*)(p + 4);
  bf16x8 r;
  r[0] = (__bf16)u0[0]; r[1] = (__bf16)u0[1]; r[2] = (__bf16)u0[2]; r[3] = (__bf16)u0[3];
  r[4] = (__bf16)u1[0]; r[5] = (__bf16)u1[1]; r[6] = (__bf16)u1[2]; r[7] = (__bf16)u1[3];
  return r;
}

__global__ __launch_bounds__(256) void convert_w_kernel(
    const float* __restrict__ qkv_w, const float* __restrict__ proj_w,
    __bf16* __restrict__ wq, __bf16* __restrict__ wp) {
  const int i = blockIdx.x * 256 + threadIdx.x;
  if (i < WQ_ELEMS) wq[i] = (__bf16)qkv_w[i];
  if (i < WP_ELEMS) wp[i] = (__bf16)proj_w[i];
}

// ============ Kernel A: per-window QKV GEMM -> ws (q scaled, v transposed) ============
__global__ __launch_bounds__(384, 3) void qkv_kernel(
    const float* __restrict__ x, const float* __restrict__ qkv_b,
    const __bf16* __restrict__ wq,
    __bf16* __restrict__ oq, __bf16* __restrict__ ok, __bf16* __restrict__ ov)
{
  __shared__ __bf16 xw[64 * 200];
  const f32x4 fz = {0.f, 0.f, 0.f, 0.f};
  const int tid = threadIdx.x, lane = tid & 63, wv = tid >> 6;
  const int li = lane & 15, g = lane >> 4;
  const int bid = blockIdx.x;
  const int wid = (bid & 7) * (NBLK / 8) + (bid >> 3);   // XCD-aware bijective
  const int b = wid / NWIN_PER_B, wr = wid % NWIN_PER_B;
  const int d0 = (wr / 144) * 4, h0 = ((wr / 12) % 12) * 4, w0 = (wr % 12) * 4;

  // stage x window -> bf16 [n][c], zero-pad d>=46 / h>=47
  #pragma unroll
  for (int rep = 0; rep < 8; ++rep) {
    const int task = rep * 384 + tid;          // < 3072
    const int c = task % Cdim, ph = task / Cdim;
    const int dd = ph >> 2, hh = ph & 3;
    const int d = d0 + dd, hs = h0 + hh;
    f32x4 v = fz;
    if (d < Dd && hs < Hh)
      v = *(const f32x4*)(x + ((size_t)(b * Cdim + c) * Dd + d) * HWst + hs * Wl + w0);
    const int nb = (dd * 16 + hh * 4) * 200 + c;
    xw[nb]       = (__bf16)v[0];
    xw[nb + 200] = (__bf16)v[1];
    xw[nb + 400] = (__bf16)v[2];
    xw[nb + 600] = (__bf16)v[3];
  }
  __syncthreads();

  // wave wv handles cols [wv*32, wv*32+32) of each of q,k,v
  f32x4 acc[3][2][4];
  #pragma unroll
  for (int p = 0; p < 3; ++p)
    #pragma unroll
    for (int i = 0; i < 2; ++i)
      #pragma unroll
      for (int rt = 0; rt < 4; ++rt) acc[p][i][rt] = fz;

  #pragma unroll
  for (int kk = 0; kk < 6; ++kk) {
    const int k0 = kk * 32 + g * 8;
    bf16x8 af[4];
    #pragma unroll
    for (int rt = 0; rt < 4; ++rt)
      af[rt] = *(const bf16x8*)&xw[(rt * 16 + li) * 200 + k0];
    #pragma unroll
    for (int p = 0; p < 3; ++p)
      #pragma unroll
      for (int i = 0; i < 2; ++i) {
        const int j = p * 192 + (wv * 2 + i) * 16 + li;
        bf16x8 bf = *(const bf16x8*)(wq + (size_t)j * Cdim + k0);
        #pragma unroll
        for (int rt = 0; rt < 4; ++rt)
          acc[p][i][rt] = MFMA16(af[rt], bf, acc[p][i][rt]);
      }
  }
  // epilogue: bias (+q scale), scatter to ws
  #pragma unroll
  for (int p = 0; p < 3; ++p)
    #pragma unroll
    for (int i = 0; i < 2; ++i) {
      const int c = (wv * 2 + i) * 16 + li;
      const float bias = qkv_b[p * 192 + c];
      #pragma unroll
      for (int rt = 0; rt < 4; ++rt)
        #pragma unroll
        for (int r = 0; r < 4; ++r) {
          float val = acc[p][i][rt][r] + bias;
          if (p == 0) val *= SCALE;
          const int n = rt * 16 + g * 4 + r;
          if (p == 0)      oq[((size_t)wid * 64 + n) * 192 + c] = (__bf16)val;
          else if (p == 1) ok[((size_t)wid * 64 + n) * 192 + c] = (__bf16)val;
          else             ov[((size_t)wid * 192 + c) * 64 + n] = (__bf16)val;
        }
    }
}

// ============ Kernel B: per-window attention + proj (qkv frags direct from ws) ============
__global__ __launch_bounds__(384, 3) void attn_kernel(
    const __bf16* __restrict__ wsq, const __bf16* __restrict__ wsk,
    const __bf16* __restrict__ wsv, const __bf16* __restrict__ wp,
    const float* __restrict__ proj_b, const float* __restrict__ rpb,
    float* __restrict__ out)
{
  __shared__ __bf16 ao[64 * 200];    // attn_out [n][c]
  __shared__ __bf16 ps[6 * 16 * 72]; // per-wave P scratch
  __shared__ float  rps[2058];
  const f32x4 fz = {0.f, 0.f, 0.f, 0.f};
  const int tid = threadIdx.x, lane = tid & 63, wv = tid >> 6;  // wv = head
  const int li = lane & 15, g = lane >> 4;
  const int hq = wv;
  const int bid = blockIdx.x;
  const int wid = (bid & 7) * (NBLK / 8) + (bid >> 3);
  const int b = wid / NWIN_PER_B, wr = wid % NWIN_PER_B;
  const int d0 = (wr / 144) * 4, h0 = ((wr / 12) % 12) * 4, w0 = (wr % 12) * 4;

  for (int i = tid; i < 343 * NHd; i += 384) rps[i] = rpb[i];

  // fragment loads straight from ws (already in MFMA fragment order)
  bf16x8 qf[4], kf[4], vf[2][2];
  #pragma unroll
  for (int t = 0; t < 4; ++t) {
    qf[t] = *(const bf16x8*)(wsq + ((size_t)wid * 64 + t * 16 + li) * 192 + hq * 32 + g * 8);
    kf[t] = *(const bf16x8*)(wsk + ((size_t)wid * 64 + t * 16 + li) * 192 + hq * 32 + g * 8);
  }
  #pragma unroll
  for (int et = 0; et < 2; ++et)
    #pragma unroll
    for (int kk = 0; kk < 2; ++kk)
      vf[et][kk] = *(const bf16x8*)(wsv + ((size_t)wid * 192 + hq * 32 + et * 16 + li) * 64 + kk * 32 + g * 8);
  __syncthreads();   // rps ready

  __bf16* pw = ps + wv * 16 * 72;
  #pragma unroll 1
  for (int rb = 0; rb < 4; ++rb) {
    f32x4 s[4];
    #pragma unroll
    for (int ct = 0; ct < 4; ++ct) s[ct] = MFMA16(qf[rb], kf[ct], fz);
    // bias + row max; query: d1=rb,h1=g,w1=r  key: d2=ct,h2=li>>2,w2=li&3
    float t[4][4], rm[4] = {-3e38f, -3e38f, -3e38f, -3e38f};
    const int hterm = (g - (li >> 2) + 3) * 7 + 3 - (li & 3);
    #pragma unroll
    for (int ct = 0; ct < 4; ++ct) {
      const int idxbase = (rb - ct + 3) * 49 + hterm;
      #pragma unroll
      for (int r = 0; r < 4; ++r) {
        const float tv = s[ct][r] + rps[(idxbase + r) * NHd + hq];
        t[ct][r] = tv;
        rm[r] = fmaxf(rm[r], tv);
      }
    }
    #pragma unroll
    for (int r = 0; r < 4; ++r) {
      rm[r] = fmaxf(rm[r], __shfl_xor(rm[r], 1, 16));
      rm[r] = fmaxf(rm[r], __shfl_xor(rm[r], 2, 16));
      rm[r] = fmaxf(rm[r], __shfl_xor(rm[r], 4, 16));
      rm[r] = fmaxf(rm[r], __shfl_xor(rm[r], 8, 16));
    }
    float rs[4] = {0, 0, 0, 0};
    #pragma unroll
    for (int ct = 0; ct < 4; ++ct)
      #pragma unroll
      for (int r = 0; r < 4; ++r) {
        const float p = __expf(t[ct][r] - rm[r]);
        t[ct][r] = p;
        rs[r] += p;
      }
    #pragma unroll
    for (int r = 0; r < 4; ++r) {
      rs[r] += __shfl_xor(rs[r], 1, 16);
      rs[r] += __shfl_xor(rs[r], 2, 16);
      rs[r] += __shfl_xor(rs[r], 4, 16);
      rs[r] += __shfl_xor(rs[r], 8, 16);
    }
    // P -> A-fragment layout via wave-private LDS
    #pragma unroll
    for (int ct = 0; ct < 4; ++ct)
      #pragma unroll
      for (int r = 0; r < 4; ++r)
        pw[(g * 4 + r) * 72 + ct * 16 + li] = (__bf16)t[ct][r];
    bf16x8 pa0 = *(const bf16x8*)&pw[li * 72 + g * 8];
    bf16x8 pa1 = *(const bf16x8*)&pw[li * 72 + 32 + g * 8];
    f32x4 o[2] = {fz, fz};
    #pragma unroll
    for (int et = 0; et < 2; ++et) {
      o[et] = MFMA16(pa0, vf[et][0], o[et]);
      o[et] = MFMA16(pa1, vf[et][1], o[et]);
    }
    float inv[4];
    #pragma unroll
    for (int r = 0; r < 4; ++r) inv[r] = 1.f / rs[r];
    #pragma unroll
    for (int et = 0; et < 2; ++et)
      #pragma unroll
      for (int r = 0; r < 4; ++r)
        ao[(rb * 16 + g * 4 + r) * 200 + hq * 32 + et * 16 + li] = (__bf16)(o[et][r] * inv[r]);
  }
  __syncthreads();

  // proj: wave wv owns col tiles {wv*2, wv*2+1}
  f32x4 pacc[2][4];
  #pragma unroll
  for (int i = 0; i < 2; ++i)
    #pragma unroll
    for (int rt = 0; rt < 4; ++rt) pacc[i][rt] = fz;
  #pragma unroll
  for (int kk = 0; kk < 6; ++kk) {
    const int k0 = kk * 32 + g * 8;
    bf16x8 af[4];
    #pragma unroll
    for (int rt = 0; rt < 4; ++rt)
      af[rt] = *(const bf16x8*)&ao[(rt * 16 + li) * 200 + k0];
    #pragma unroll
    for (int i = 0; i < 2; ++i) {
      const int c = (wv * 2 + i) * 16 + li;
      bf16x8 bf = *(const bf16x8*)(wp + (size_t)c * Cdim + k0);
      #pragma unroll
      for (int rt = 0; rt < 4; ++rt)
        pacc[i][rt] = MFMA16(af[rt], bf, pacc[i][rt]);
    }
  }
  #pragma unroll
  for (int i = 0; i < 2; ++i) {
    const int c = (wv * 2 + i) * 16 + li;
    const float pb = proj_b[c];
    #pragma unroll
    for (int rt = 0; rt < 4; ++rt) {
      const int d = d0 + rt, hs = h0 + g;
      if (d < Dd && hs < Hh) {
        f32x4 vv = {pacc[i][rt][0] + pb, pacc[i][rt][1] + pb,
                    pacc[i][rt][2] + pb, pacc[i][rt][3] + pb};
        *(f32x4*)(out + ((size_t)(b * Cdim + c) * Dd + d) * HWst + hs * Wl + w0) = vv;
      }
    }
  }
}

// ============ Fallback: fused single-kernel (R3) ============
constexpr int XW_LD = 200, QK_LD = 36, VT_LD = 68, P_LD = 68;
constexpr int XW_OFF  = 0;
constexpr int Q_OFF   = 25600;
constexpr int K_OFF   = Q_OFF + 27648;
constexpr int VT_OFF  = K_OFF + 27648;
constexpr int P_OFF   = VT_OFF + 26112;
constexpr int RPB_OFF = P_OFF + 26112;
constexpr int LDS_TOTAL = RPB_OFF + 8256;

template <bool WB>
__global__ __launch_bounds__(768, 3) void winattn_fused(
    const float* __restrict__ x, const float* __restrict__ qkv_w,
    const float* __restrict__ qkv_b, const float* __restrict__ proj_w,
    const float* __restrict__ proj_b, const float* __restrict__ rpb,
    const __bf16* __restrict__ wq, const __bf16* __restrict__ wp,
    float* __restrict__ out)
{
  extern __shared__ __align__(16) char smem[];
  __bf16* xw  = (__bf16*)(smem + XW_OFF);
  __bf16* qs  = (__bf16*)(smem + Q_OFF);
  __bf16* ks  = (__bf16*)(smem + K_OFF);
  __bf16* vt  = (__bf16*)(smem + VT_OFF);
  __bf16* pl  = (__bf16*)(smem + P_OFF);
  float*  rps = (float*)(smem + RPB_OFF);
  const f32x4 fz = {0.f, 0.f, 0.f, 0.f};
  const int tid = threadIdx.x, lane = tid & 63, wv = tid >> 6;
  const int hq = wv >> 1, half = wv & 1, li = lane & 15, g = lane >> 4;
  const int bid = blockIdx.x;
  const int wid = (bid & 7) * (NBLK / 8) + (bid >> 3);
  const int b = wid / NWIN_PER_B, wr = wid % NWIN_PER_B;
  const int d0 = (wr / 144) * 4, h0 = ((wr / 12) % 12) * 4, w0 = (wr % 12) * 4;
  for (int i = tid; i < 343 * NHd; i += 768) rps[i] = rpb[i];
  #pragma unroll
  for (int rep = 0; rep < 4; ++rep) {
    const int task = rep * 768 + tid;
    const int c = task % Cdim, ph = task / Cdim;
    const int dd = ph >> 2, hh2 = ph & 3;
    const int d = d0 + dd, hsp = h0 + hh2;
    f32x4 v = fz;
    if (d < Dd && hsp < Hh)
      v = *(const f32x4*)(x + ((size_t)(b * Cdim + c) * Dd + d) * HWst + hsp * Wl + w0);
    const int nb = (dd * 16 + hh2 * 4) * XW_LD + c;
    xw[nb] = (__bf16)v[0]; xw[nb + XW_LD] = (__bf16)v[1];
    xw[nb + 2 * XW_LD] = (__bf16)v[2]; xw[nb + 3 * XW_LD] = (__bf16)v[3];
  }
  __syncthreads();
  {
    f32x4 acc[6][2];
    #pragma unroll
    for (int it = 0; it < 6; ++it)
      #pragma unroll
      for (int rr = 0; rr < 2; ++rr) acc[it][rr] = fz;
    #pragma unroll
    for (int kk = 0; kk < 6; ++kk) {
      const int k0 = kk * 32 + g * 8;
      bf16x8 af[2];
      #pragma unroll
      for (int rr = 0; rr < 2; ++rr)
        af[rr] = *(const bf16x8*)&xw[((half * 2 + rr) * 16 + li) * XW_LD + k0];
      #pragma unroll
      for (int it = 0; it < 6; ++it) {
        const int T = (it >> 1) * 12 + hq * 2 + (it & 1);
        const int j = T * 16 + li;
        bf16x8 bf;
        if constexpr (WB) bf = *(const bf16x8*)(wq + j * Cdim + k0);
        else              bf = cvt8(qkv_w + j * Cdim + k0);
        #pragma unroll
        for (int rr = 0; rr < 2; ++rr) acc[it][rr] = MFMA16(af[rr], bf, acc[it][rr]);
      }
    }
    #pragma unroll
    for (int it = 0; it < 6; ++it) {
      const int part = it >> 1, e16 = (it & 1) * 16;
      const int j0 = (part * 12 + hq * 2 + (it & 1)) * 16;
      const float qb = qkv_b[j0 + li];
      #pragma unroll
      for (int rr = 0; rr < 2; ++rr) {
        const int rb = half * 2 + rr;
        #pragma unroll
        for (int r = 0; r < 4; ++r) {
          const float val = acc[it][rr][r] + qb;
          const int n = rb * 16 + g * 4 + r;
          if (part == 0)      qs[(hq * 64 + n) * QK_LD + e16 + li] = (__bf16)val;
          else if (part == 1) ks[(hq * 64 + n) * QK_LD + e16 + li] = (__bf16)val;
          else                vt[(hq * 32 + e16 + li) * VT_LD + n] = (__bf16)val;
        }
      }
    }
  }
  __syncthreads();
  {
    __bf16* pw = pl + wv * 16 * P_LD;
    #pragma unroll 1
    for (int rr = 0; rr < 2; ++rr) {
      const int rb = half * 2 + rr;
      bf16x8 aq = *(const bf16x8*)&qs[(hq * 64 + rb * 16 + li) * QK_LD + g * 8];
      f32x4 s[4];
      #pragma unroll
      for (int ct = 0; ct < 4; ++ct) {
        bf16x8 bk = *(const bf16x8*)&ks[(hq * 64 + ct * 16 + li) * QK_LD + g * 8];
        s[ct] = MFMA16(aq, bk, fz);
      }
      float t[4][4], rm[4] = {-3e38f, -3e38f, -3e38f, -3e38f};
      #pragma unroll
      for (int ct = 0; ct < 4; ++ct) {
        #pragma unroll
        for (int r = 0; r < 4; ++r) {
          const int idx = (rb - ct + 3) * 49 + (g - (li >> 2) + 3) * 7 + (r - (li & 3) + 3);
          const float tv = s[ct][r] * SCALE + rps[idx * NHd + hq];
          t[ct][r] = tv;
          rm[r] = fmaxf(rm[r], tv);
        }
      }
      #pragma unroll
      for (int r = 0; r < 4; ++r) {
        rm[r] = fmaxf(rm[r], __shfl_xor(rm[r], 1, 16));
        rm[r] = fmaxf(rm[r], __shfl_xor(rm[r], 2, 16));
        rm[r] = fmaxf(rm[r], __shfl_xor(rm[r], 4, 16));
        rm[r] = fmaxf(rm[r], __shfl_xor(rm[r], 8, 16));
      }
      float rs[4] = {0, 0, 0, 0};
      #pragma unroll
      for (int ct = 0; ct < 4; ++ct)
        #pragma unroll
        for (int r = 0; r < 4; ++r) {
          const float p = __expf(t[ct][r] - rm[r]);
          t[ct][r] = p; rs[r] += p;
        }
      #pragma unroll
      for (int r = 0; r < 4; ++r) {
        rs[r] += __shfl_xor(rs[r], 1, 16);
        rs[r] += __shfl_xor(rs[r], 2, 16);
        rs[r] += __shfl_xor(rs[r], 4, 16);
        rs[r] += __shfl_xor(rs[r], 8, 16);
      }
      #pragma unroll
      for (int ct = 0; ct < 4; ++ct)
        #pragma unroll
        for (int r = 0; r < 4; ++r)
          pw[(g * 4 + r) * P_LD + ct * 16 + li] = (__bf16)t[ct][r];
      f32x4 o[2] = {fz, fz};
      #pragma unroll
      for (int kk = 0; kk < 2; ++kk) {
        bf16x8 ap = *(const bf16x8*)&pw[li * P_LD + kk * 32 + g * 8];
        #pragma unroll
        for (int ct = 0; ct < 2; ++ct) {
          bf16x8 bv = *(const bf16x8*)&vt[(hq * 32 + ct * 16 + li) * VT_LD + kk * 32 + g * 8];
          o[ct] = MFMA16(ap, bv, o[ct]);
        }
      }
      float inv[4];
      #pragma unroll
      for (int r = 0; r < 4; ++r) inv[r] = 1.f / rs[r];
      #pragma unroll
      for (int ct = 0; ct < 2; ++ct)
        #pragma unroll
        for (int r = 0; r < 4; ++r)
          xw[(rb * 16 + g * 4 + r) * XW_LD + hq * 32 + ct * 16 + li] = (__bf16)(o[ct][r] * inv[r]);
    }
  }
  __syncthreads();
  {
    f32x4 acc[4];
    #pragma unroll
    for (int rt = 0; rt < 4; ++rt) acc[rt] = fz;
    const int c = wv * 16 + li;
    #pragma unroll
    for (int kk = 0; kk < 6; ++kk) {
      const int k0 = kk * 32 + g * 8;
      bf16x8 bf;
      if constexpr (WB) bf = *(const bf16x8*)(wp + c * Cdim + k0);
      else              bf = cvt8(proj_w + c * Cdim + k0);
      #pragma unroll
      for (int rt = 0; rt < 4; ++rt) {
        bf16x8 af = *(const bf16x8*)&xw[(rt * 16 + li) * XW_LD + k0];
        acc[rt] = MFMA16(af, bf, acc[rt]);
      }
    }
    const float pb = proj_b[c];
    #pragma unroll
    for (int rt = 0; rt < 4; ++rt) {
      const int d = d0 + rt, hsp = h0 + g;
      if (d < Dd && hsp < Hh) {
        f32x4 vv = {acc[rt][0] + pb, acc[rt][1] + pb, acc[rt][2] + pb, acc[rt][3] + pb};
        *(f32x4*)(out + ((size_t)(b * Cdim + c) * Dd + d) * HWst + hsp * Wl + w0) = vv;
      }
    }
  }
}

extern "C" void kernel_launch(void* const* d_in, const int* in_sizes, int n_in,
                              void* d_out, int out_size, void* d_ws, size_t ws_size,
                              hipStream_t stream) {
  const float* x      = (const float*)d_in[0];
  const float* qkv_w  = (const float*)d_in[1];
  const float* qkv_b  = (const float*)d_in[2];
  const float* proj_w = (const float*)d_in[3];
  const float* proj_b = (const float*)d_in[4];
  const float* rpb    = (const float*)d_in[5];
  float* out = (float*)d_out;

  if (ws_size >= WS_FULL) {
    __bf16* wsb = (__bf16*)d_ws;
    __bf16* wq = wsb + OFF_WQ;
    __bf16* wp = wsb + OFF_WP;
    __bf16* q  = wsb + OFF_Q;
    __bf16* k  = wsb + OFF_K;
    __bf16* v  = wsb + OFF_V;
    convert_w_kernel<<<(WQ_ELEMS + 255) / 256, 256, 0, stream>>>(qkv_w, proj_w, wq, wp);
    qkv_kernel<<<NBLK, 384, 0, stream>>>(x, qkv_b, wq, q, k, v);
    attn_kernel<<<NBLK, 384, 0, stream>>>(q, k, v, wp, proj_b, rpb, out);
  } else if (ws_size >= WS_W) {
    __bf16* wq = (__bf16*)d_ws;
    __bf16* wp = wq + WQ_ELEMS;
    convert_w_kernel<<<(WQ_ELEMS + 255) / 256, 256, 0, stream>>>(qkv_w, proj_w, wq, wp);
    (void)hipFuncSetAttribute(reinterpret_cast<const void*>(&winattn_fused<true>),
                              hipFuncAttributeMaxDynamicSharedMemorySize, LDS_TOTAL);
    winattn_fused<true><<<NBLK, 768, LDS_TOTAL, stream>>>(
        x, qkv_w, qkv_b, proj_w, proj_b, rpb, wq, wp, out);
  } else {
    (void)hipFuncSetAttribute(reinterpret_cast<const void*>(&winattn_fused<false>),
                              hipFuncAttributeMaxDynamicSharedMemorySize, LDS_TOTAL);
    winattn_fused<false><<<NBLK, 768, LDS_TOTAL, stream>>>(
        x, qkv_w, qkv_b, proj_w, proj_b, rpb, nullptr, nullptr, out);
  }
}